// Round 1
// 764.174 us; speedup vs baseline: 1.1203x; 1.1203x over previous
//
#include <hip/hip_runtime.h>
#include <math.h>

#define B_   2
#define S_   3072
#define C_   256
#define NH   8
#define HD   32
#define HALF 16
#define NELEM (B_*S_*C_)   // 1,572,864

__device__ __forceinline__ float dot4(float4 a, float4 b) {
    return a.x*b.x + a.y*b.y + a.z*b.z + a.w*b.w;
}

// ---------------- GEMM: out[M x 256] = A[M x 256] @ W[256 x 256]^T (+bias) ---------
// 64x64 tile, 256 threads, 4x4 microtile, K staged in 32-wide chunks.
__device__ __forceinline__ void gemm_nt_body(const float* __restrict__ A,
                                             const float* __restrict__ W,
                                             const float* __restrict__ bias,
                                             float* __restrict__ out)
{
    __shared__ float As[64][36];   // +4 pad keeps float4 alignment, breaks some conflicts
    __shared__ float Ws[64][36];
    const int tid  = threadIdx.x;
    const int tx4  = (tid & 15) * 4;   // col group
    const int ty4  = (tid >> 4) * 4;   // row group
    const int row0 = blockIdx.x * 64;
    const int col0 = blockIdx.y * 64;

    float acc[4][4] = {};

    for (int kc = 0; kc < C_; kc += 32) {
        __syncthreads();
        #pragma unroll
        for (int l = tid; l < 512; l += 256) {
            const int r  = l >> 3;
            const int k4 = (l & 7) * 4;
            *(float4*)&As[r][k4] = *(const float4*)&A[(size_t)(row0 + r)*C_ + kc + k4];
            *(float4*)&Ws[r][k4] = *(const float4*)&W[(size_t)(col0 + r)*C_ + kc + k4];
        }
        __syncthreads();
        #pragma unroll
        for (int k4 = 0; k4 < 32; k4 += 4) {
            float4 a0 = *(const float4*)&As[ty4+0][k4];
            float4 a1 = *(const float4*)&As[ty4+1][k4];
            float4 a2 = *(const float4*)&As[ty4+2][k4];
            float4 a3 = *(const float4*)&As[ty4+3][k4];
            float4 w0 = *(const float4*)&Ws[tx4+0][k4];
            float4 w1 = *(const float4*)&Ws[tx4+1][k4];
            float4 w2 = *(const float4*)&Ws[tx4+2][k4];
            float4 w3 = *(const float4*)&Ws[tx4+3][k4];
            acc[0][0] += dot4(a0,w0); acc[0][1] += dot4(a0,w1);
            acc[0][2] += dot4(a0,w2); acc[0][3] += dot4(a0,w3);
            acc[1][0] += dot4(a1,w0); acc[1][1] += dot4(a1,w1);
            acc[1][2] += dot4(a1,w2); acc[1][3] += dot4(a1,w3);
            acc[2][0] += dot4(a2,w0); acc[2][1] += dot4(a2,w1);
            acc[2][2] += dot4(a2,w2); acc[2][3] += dot4(a2,w3);
            acc[3][0] += dot4(a3,w0); acc[3][1] += dot4(a3,w1);
            acc[3][2] += dot4(a3,w2); acc[3][3] += dot4(a3,w3);
        }
    }

    float4 bv = make_float4(0.f, 0.f, 0.f, 0.f);
    if (bias) bv = *(const float4*)&bias[col0 + tx4];
    #pragma unroll
    for (int rr = 0; rr < 4; ++rr) {
        float4 o = make_float4(acc[rr][0] + bv.x, acc[rr][1] + bv.y,
                               acc[rr][2] + bv.z, acc[rr][3] + bv.w);
        *(float4*)&out[(size_t)(row0 + ty4 + rr)*C_ + col0 + tx4] = o;
    }
}

__global__ __launch_bounds__(256) void qkv_kernel(
        const float* __restrict__ x,
        const float* __restrict__ Wq, const float* __restrict__ Wk, const float* __restrict__ Wv,
        const float* __restrict__ qb, const float* __restrict__ vb,
        float* __restrict__ q, float* __restrict__ k, float* __restrict__ v)
{
    if      (blockIdx.z == 0) gemm_nt_body(x, Wq, qb,      q);
    else if (blockIdx.z == 1) gemm_nt_body(x, Wk, nullptr, k);
    else                      gemm_nt_body(x, Wv, vb,      v);
}

__global__ __launch_bounds__(256) void out_gemm_kernel(
        const float* __restrict__ ctx, const float* __restrict__ Wo,
        const float* __restrict__ bo, float* __restrict__ out)
{
    gemm_nt_body(ctx, Wo, bo, out);
}

// ---------------- RoPE (in place on q and k), phase in double --------------------
__global__ __launch_bounds__(256) void rope_kernel(float* __restrict__ q, float* __restrict__ k)
{
    const int idx = blockIdx.x * 256 + threadIdx.x;   // grid sized exactly
    const int per_tensor = B_ * S_ * NH * HALF;       // 786432
    float* t = (idx < per_tensor) ? q : k;
    const int i   = (idx < per_tensor) ? idx : idx - per_tensor;
    const int j   = i & 15;
    const int hh  = (i >> 4) & 7;
    const int row = i >> 7;                            // 0 .. B_*S_-1
    const int s   = (row >= S_) ? (row - S_) : row;    // position within batch

    const double invf = exp(-log(10000.0) * (double)j * (1.0 / 16.0));
    // match reference: angle formed in fp32, then accurate sin/cos of that angle
    const float  angf = (float)((double)s * invf);
    double sn, cs;
    sincos((double)angf, &sn, &cs);
    const float c = (float)cs, sf = (float)sn;

    const size_t base = (size_t)row * C_ + hh * HD + j;
    const float t1 = t[base];
    const float t2 = t[base + HALF];
    t[base]        = t1 * c - t2 * sf;
    t[base + HALF] = t2 * c + t1 * sf;
}

// ---------------- Flash attention, fp32 ------------------------------------------
// grid (S_/64, NH, B_), 128 threads (2 waves). Thread t: rows {qb+(t>>2), qb+(t>>2)+32},
// col sub-group sub = t&3 handles score cols c = sub + 4*i.
// 768 blocks = exactly 3 resident blocks per CU (VGPR cap is 2 waves/SIMD -> 4 blocks),
// fixing the 1.5-blocks/CU imbalance of the 384x4-wave version.
// PV loop fused across the two rows so each Vs float4 read feeds 8 FMAs (was 4).
__global__ __launch_bounds__(128) void attn_kernel(
        const float* __restrict__ q, const float* __restrict__ k,
        const float* __restrict__ v, float* __restrict__ ctx)
{
    __shared__ float Ks[64][36];
    __shared__ float Vs[64][36];

    const int tid = threadIdx.x;
    const int sub = tid & 3;
    const int rr  = tid >> 2;                 // 0..31
    const int qb  = blockIdx.x * 64;
    const int hh  = blockIdx.y;
    const int b   = blockIdx.z;
    const size_t rowbase = (size_t)b * S_;
    const int coloff = hh * HD;

    const float scale = 0.17677669529663687f; // 1/sqrt(32), folded into q
    const int r0 = qb + rr, r1 = qb + rr + 32;

    float qreg0[32], qreg1[32];
    #pragma unroll
    for (int k4 = 0; k4 < 32; k4 += 4) {
        float4 t0 = *(const float4*)&q[(rowbase + r0)*C_ + coloff + k4];
        float4 t1 = *(const float4*)&q[(rowbase + r1)*C_ + coloff + k4];
        qreg0[k4+0]=t0.x*scale; qreg0[k4+1]=t0.y*scale; qreg0[k4+2]=t0.z*scale; qreg0[k4+3]=t0.w*scale;
        qreg1[k4+0]=t1.x*scale; qreg1[k4+1]=t1.y*scale; qreg1[k4+2]=t1.z*scale; qreg1[k4+3]=t1.w*scale;
    }

    float m0 = -1e30f, m1 = -1e30f, l0 = 0.f, l1 = 0.f;
    float acc0[32] = {}, acc1[32] = {};

    for (int kt = 0; kt < S_; kt += 64) {
        __syncthreads();                       // previous tile consumers done
        #pragma unroll
        for (int l = tid; l < 512; l += 128) {
            const int r  = l >> 3;
            const int k4 = (l & 7) * 4;
            *(float4*)&Ks[r][k4] = *(const float4*)&k[(rowbase + kt + r)*C_ + coloff + k4];
            *(float4*)&Vs[r][k4] = *(const float4*)&v[(rowbase + kt + r)*C_ + coloff + k4];
        }
        __syncthreads();

        // ---- scores for 16 cols x 2 rows (Ks read shared across both rows)
        float sc0[16], sc1[16];
        #pragma unroll
        for (int i = 0; i < 16; ++i) {
            const int c = sub + 4*i;           // rows 4 apart across sub -> conflict-free
            float d0 = 0.f, d1 = 0.f;
            #pragma unroll
            for (int k4 = 0; k4 < 32; k4 += 4) {
                float4 kk = *(const float4*)&Ks[c][k4];
                d0 += qreg0[k4+0]*kk.x + qreg0[k4+1]*kk.y + qreg0[k4+2]*kk.z + qreg0[k4+3]*kk.w;
                d1 += qreg1[k4+0]*kk.x + qreg1[k4+1]*kk.y + qreg1[k4+2]*kk.z + qreg1[k4+3]*kk.w;
            }
            sc0[i] = d0; sc1[i] = d1;
        }

        // ---- online softmax bookkeeping, both rows
        {
            float tm0 = sc0[0], tm1 = sc1[0];
            #pragma unroll
            for (int i = 1; i < 16; ++i) { tm0 = fmaxf(tm0, sc0[i]); tm1 = fmaxf(tm1, sc1[i]); }
            tm0 = fmaxf(tm0, __shfl_xor(tm0, 1));
            tm0 = fmaxf(tm0, __shfl_xor(tm0, 2));
            tm1 = fmaxf(tm1, __shfl_xor(tm1, 1));
            tm1 = fmaxf(tm1, __shfl_xor(tm1, 2));
            const float mnew0 = fmaxf(m0, tm0);
            const float mnew1 = fmaxf(m1, tm1);
            const float f0 = __expf(m0 - mnew0);
            const float f1 = __expf(m1 - mnew1);
            m0 = mnew0; m1 = mnew1; l0 *= f0; l1 *= f1;
            #pragma unroll
            for (int dd = 0; dd < 32; ++dd) { acc0[dd] *= f0; acc1[dd] *= f1; }
            #pragma unroll
            for (int i = 0; i < 16; ++i) {
                float p0 = __expf(sc0[i] - mnew0); sc0[i] = p0; l0 += p0;
                float p1 = __expf(sc1[i] - mnew1); sc1[i] = p1; l1 += p1;
            }
        }

        // ---- PV, fused over both rows: each Vs float4 read feeds 8 FMAs
        #pragma unroll
        for (int i = 0; i < 16; ++i) {
            const int c = sub + 4*i;
            const float p0 = sc0[i];
            const float p1 = sc1[i];
            #pragma unroll
            for (int d4 = 0; d4 < 8; ++d4) {
                float4 vv = *(const float4*)&Vs[c][d4*4];
                acc0[d4*4+0] += p0*vv.x; acc0[d4*4+1] += p0*vv.y;
                acc0[d4*4+2] += p0*vv.z; acc0[d4*4+3] += p0*vv.w;
                acc1[d4*4+0] += p1*vv.x; acc1[d4*4+1] += p1*vv.y;
                acc1[d4*4+2] += p1*vv.z; acc1[d4*4+3] += p1*vv.w;
            }
        }
    }

    // ---- reduce across the 4-lane row group, normalize, write
    l0 += __shfl_xor(l0, 1); l0 += __shfl_xor(l0, 2);
    l1 += __shfl_xor(l1, 1); l1 += __shfl_xor(l1, 2);
    const float inv0 = 1.f / l0, inv1 = 1.f / l1;
    #pragma unroll
    for (int dd = 0; dd < 32; ++dd) {
        float a = acc0[dd]; a += __shfl_xor(a, 1); a += __shfl_xor(a, 2); acc0[dd] = a * inv0;
        float c2 = acc1[dd]; c2 += __shfl_xor(c2, 1); c2 += __shfl_xor(c2, 2); acc1[dd] = c2 * inv1;
    }
    // static-index writes: 4-way branch on sub (keeps register arrays out of scratch)
    #define WRITE_SLICE(ro, a_, off) { \
        float4 o1 = make_float4(a_[(off)+0],a_[(off)+1],a_[(off)+2],a_[(off)+3]); \
        float4 o2 = make_float4(a_[(off)+4],a_[(off)+5],a_[(off)+6],a_[(off)+7]); \
        *(float4*)&ctx[(rowbase + (ro))*C_ + coloff + (off)]     = o1; \
        *(float4*)&ctx[(rowbase + (ro))*C_ + coloff + (off) + 4] = o2; }
    if      (sub == 0) { WRITE_SLICE(r0, acc0, 0)  WRITE_SLICE(r1, acc1, 0)  }
    else if (sub == 1) { WRITE_SLICE(r0, acc0, 8)  WRITE_SLICE(r1, acc1, 8)  }
    else if (sub == 2) { WRITE_SLICE(r0, acc0, 16) WRITE_SLICE(r1, acc1, 16) }
    else               { WRITE_SLICE(r0, acc0, 24) WRITE_SLICE(r1, acc1, 24) }
    #undef WRITE_SLICE
}

// ---------------- launch ---------------------------------------------------------
extern "C" void kernel_launch(void* const* d_in, const int* in_sizes, int n_in,
                              void* d_out, int out_size, void* d_ws, size_t ws_size,
                              hipStream_t stream)
{
    const float* x  = (const float*)d_in[0];
    const float* Wq = (const float*)d_in[1];
    const float* Wk = (const float*)d_in[2];
    const float* Wv = (const float*)d_in[3];
    const float* qb = (const float*)d_in[4];
    const float* vb = (const float*)d_in[5];
    const float* Wo = (const float*)d_in[6];
    const float* bo = (const float*)d_in[7];
    float* out = (float*)d_out;

    float* ws  = (float*)d_ws;
    float* q   = ws;
    float* k   = q + NELEM;
    float* v   = k + NELEM;
    float* ctx = v + NELEM;

    // q,k,v projections (+bias), 64x64 tiles: grid 96 x 4, z selects matrix
    qkv_kernel<<<dim3(96, 4, 3), 256, 0, stream>>>(x, Wq, Wk, Wv, qb, vb, q, k, v);
    // RoPE in place on q (scale folded later) and k
    rope_kernel<<<6144, 256, 0, stream>>>(q, k);
    // flash attention: 768 blocks of 128 threads (64 q-rows each)
    attn_kernel<<<dim3(S_/64, NH, B_), 128, 0, stream>>>(q, k, v, ctx);
    // output projection
    out_gemm_kernel<<<dim3(96, 4, 1), 256, 0, stream>>>(ctx, Wo, bo, out);
}

// Round 2
// 680.953 us; speedup vs baseline: 1.2573x; 1.1222x over previous
//
#include <hip/hip_runtime.h>
#include <math.h>

#define B_   2
#define S_   3072
#define C_   256
#define NH   8
#define HD   32
#define HALF 16
#define NELEM (B_*S_*C_)   // 1,572,864

__device__ __forceinline__ float dot4(float4 a, float4 b) {
    return a.x*b.x + a.y*b.y + a.z*b.z + a.w*b.w;
}

// ---------------- GEMM: out[M x 256] = A[M x 256] @ W[256 x 256]^T (+bias) ---------
// 64x64 tile, 256 threads, 4x4 microtile, K staged in 32-wide chunks.
__device__ __forceinline__ void gemm_nt_body(const float* __restrict__ A,
                                             const float* __restrict__ W,
                                             const float* __restrict__ bias,
                                             float* __restrict__ out)
{
    __shared__ float As[64][36];   // +4 pad keeps float4 alignment, breaks some conflicts
    __shared__ float Ws[64][36];
    const int tid  = threadIdx.x;
    const int tx4  = (tid & 15) * 4;   // col group
    const int ty4  = (tid >> 4) * 4;   // row group
    const int row0 = blockIdx.x * 64;
    const int col0 = blockIdx.y * 64;

    float acc[4][4] = {};

    for (int kc = 0; kc < C_; kc += 32) {
        __syncthreads();
        #pragma unroll
        for (int l = tid; l < 512; l += 256) {
            const int r  = l >> 3;
            const int k4 = (l & 7) * 4;
            *(float4*)&As[r][k4] = *(const float4*)&A[(size_t)(row0 + r)*C_ + kc + k4];
            *(float4*)&Ws[r][k4] = *(const float4*)&W[(size_t)(col0 + r)*C_ + kc + k4];
        }
        __syncthreads();
        #pragma unroll
        for (int k4 = 0; k4 < 32; k4 += 4) {
            float4 a0 = *(const float4*)&As[ty4+0][k4];
            float4 a1 = *(const float4*)&As[ty4+1][k4];
            float4 a2 = *(const float4*)&As[ty4+2][k4];
            float4 a3 = *(const float4*)&As[ty4+3][k4];
            float4 w0 = *(const float4*)&Ws[tx4+0][k4];
            float4 w1 = *(const float4*)&Ws[tx4+1][k4];
            float4 w2 = *(const float4*)&Ws[tx4+2][k4];
            float4 w3 = *(const float4*)&Ws[tx4+3][k4];
            acc[0][0] += dot4(a0,w0); acc[0][1] += dot4(a0,w1);
            acc[0][2] += dot4(a0,w2); acc[0][3] += dot4(a0,w3);
            acc[1][0] += dot4(a1,w0); acc[1][1] += dot4(a1,w1);
            acc[1][2] += dot4(a1,w2); acc[1][3] += dot4(a1,w3);
            acc[2][0] += dot4(a2,w0); acc[2][1] += dot4(a2,w1);
            acc[2][2] += dot4(a2,w2); acc[2][3] += dot4(a2,w3);
            acc[3][0] += dot4(a3,w0); acc[3][1] += dot4(a3,w1);
            acc[3][2] += dot4(a3,w2); acc[3][3] += dot4(a3,w3);
        }
    }

    float4 bv = make_float4(0.f, 0.f, 0.f, 0.f);
    if (bias) bv = *(const float4*)&bias[col0 + tx4];
    #pragma unroll
    for (int rr = 0; rr < 4; ++rr) {
        float4 o = make_float4(acc[rr][0] + bv.x, acc[rr][1] + bv.y,
                               acc[rr][2] + bv.z, acc[rr][3] + bv.w);
        *(float4*)&out[(size_t)(row0 + ty4 + rr)*C_ + col0 + tx4] = o;
    }
}

__global__ __launch_bounds__(256) void qkv_kernel(
        const float* __restrict__ x,
        const float* __restrict__ Wq, const float* __restrict__ Wk, const float* __restrict__ Wv,
        const float* __restrict__ qb, const float* __restrict__ vb,
        float* __restrict__ q, float* __restrict__ k, float* __restrict__ v)
{
    if      (blockIdx.z == 0) gemm_nt_body(x, Wq, qb,      q);
    else if (blockIdx.z == 1) gemm_nt_body(x, Wk, nullptr, k);
    else                      gemm_nt_body(x, Wv, vb,      v);
}

__global__ __launch_bounds__(256) void out_gemm_kernel(
        const float* __restrict__ ctx, const float* __restrict__ Wo,
        const float* __restrict__ bo, float* __restrict__ out)
{
    gemm_nt_body(ctx, Wo, bo, out);
}

// ---------------- RoPE (in place on q and k), phase in double --------------------
__global__ __launch_bounds__(256) void rope_kernel(float* __restrict__ q, float* __restrict__ k)
{
    const int idx = blockIdx.x * 256 + threadIdx.x;   // grid sized exactly
    const int per_tensor = B_ * S_ * NH * HALF;       // 786432
    float* t = (idx < per_tensor) ? q : k;
    const int i   = (idx < per_tensor) ? idx : idx - per_tensor;
    const int j   = i & 15;
    const int hh  = (i >> 4) & 7;
    const int row = i >> 7;                            // 0 .. B_*S_-1
    const int s   = (row >= S_) ? (row - S_) : row;    // position within batch

    const double invf = exp(-log(10000.0) * (double)j * (1.0 / 16.0));
    // match reference: angle formed in fp32, then accurate sin/cos of that angle
    const float  angf = (float)((double)s * invf);
    double sn, cs;
    sincos((double)angf, &sn, &cs);
    const float c = (float)cs, sf = (float)sn;

    const size_t base = (size_t)row * C_ + hh * HD + j;
    const float t1 = t[base];
    const float t2 = t[base + HALF];
    t[base]        = t1 * c - t2 * sf;
    t[base + HALF] = t2 * c + t1 * sf;
}

// ---------------- softmax helpers: tree reductions (short dep chains) -------------
__device__ __forceinline__ float tree_max16(const float s[16]) {
    float t[8];
    #pragma unroll
    for (int i = 0; i < 8; ++i) t[i] = fmaxf(s[i], s[i+8]);
    #pragma unroll
    for (int i = 0; i < 4; ++i) t[i] = fmaxf(t[i], t[i+4]);
    t[0] = fmaxf(t[0], t[2]); t[1] = fmaxf(t[1], t[3]);
    return fmaxf(t[0], t[1]);
}
__device__ __forceinline__ float tree_sum16(const float s[16]) {
    float t[8];
    #pragma unroll
    for (int i = 0; i < 8; ++i) t[i] = s[i] + s[i+8];
    #pragma unroll
    for (int i = 0; i < 4; ++i) t[i] = t[i] + t[i+4];
    return (t[0] + t[2]) + (t[1] + t[3]);
}

// ---------------- Flash attention, fp32 ------------------------------------------
// grid (S_/64, NH, B_), 128 threads (2 waves). Thread t: rows {qb+(t>>2), qb+(t>>2)+32},
// col sub-group sub = t&3 handles score cols c = sub + 4*i.
//
// Software pipeline (T14 async-split + LDS double buffer, ONE barrier per tile):
//   loop t: [ds_write regs(tile t+1) -> buf[nxt]]  (regs loaded at t-1)
//           [issue global loads tile t+2 -> regs]  (latency hides under compute)
//           [compute tile t from buf[cur]]         (setprio(1) around it)
//           [__syncthreads()]
// This removes the barrier-serialized global-load wait that capped VALUBusy at 36%.
__global__ __launch_bounds__(128) void attn_kernel(
        const float* __restrict__ q, const float* __restrict__ k,
        const float* __restrict__ v, float* __restrict__ ctx)
{
    __shared__ float Ks[2][64][36];
    __shared__ float Vs[2][64][36];

    const int tid = threadIdx.x;
    const int sub = tid & 3;
    const int rr  = tid >> 2;                 // 0..31
    const int qb  = blockIdx.x * 64;
    const int hh  = blockIdx.y;
    const int b   = blockIdx.z;
    const size_t rowbase = (size_t)b * S_;
    const int coloff = hh * HD;

    // staging decomposition: thread tid loads rows sr+{0,16,32,48}, cols [sk, sk+4)
    const int sr = tid >> 3;                  // 0..15
    const int sk = (tid & 7) * 4;             // 0,4,...,28
    const float* kptr = &k[rowbase*C_ + coloff + sk];
    const float* vptr = &v[rowbase*C_ + coloff + sk];

    const float scale = 0.17677669529663687f; // 1/sqrt(32), folded into q
    const int r0 = qb + rr, r1 = qb + rr + 32;

    float qreg0[32], qreg1[32];
    #pragma unroll
    for (int k4 = 0; k4 < 32; k4 += 4) {
        float4 t0 = *(const float4*)&q[(rowbase + r0)*C_ + coloff + k4];
        float4 t1 = *(const float4*)&q[(rowbase + r1)*C_ + coloff + k4];
        qreg0[k4+0]=t0.x*scale; qreg0[k4+1]=t0.y*scale; qreg0[k4+2]=t0.z*scale; qreg0[k4+3]=t0.w*scale;
        qreg1[k4+0]=t1.x*scale; qreg1[k4+1]=t1.y*scale; qreg1[k4+2]=t1.z*scale; qreg1[k4+3]=t1.w*scale;
    }

    float4 kr0, kr1, kr2, kr3, vr0, vr1, vr2, vr3;

#define LOAD_TILE(kt) { \
        const size_t o = (size_t)((kt) + sr) * C_; \
        kr0 = *(const float4*)&kptr[o          ]; \
        kr1 = *(const float4*)&kptr[o + 16*C_  ]; \
        kr2 = *(const float4*)&kptr[o + 32*C_  ]; \
        kr3 = *(const float4*)&kptr[o + 48*C_  ]; \
        vr0 = *(const float4*)&vptr[o          ]; \
        vr1 = *(const float4*)&vptr[o + 16*C_  ]; \
        vr2 = *(const float4*)&vptr[o + 32*C_  ]; \
        vr3 = *(const float4*)&vptr[o + 48*C_  ]; }

#define WRITE_TILE(bufi) { \
        *(float4*)&Ks[bufi][sr+ 0][sk] = kr0; \
        *(float4*)&Ks[bufi][sr+16][sk] = kr1; \
        *(float4*)&Ks[bufi][sr+32][sk] = kr2; \
        *(float4*)&Ks[bufi][sr+48][sk] = kr3; \
        *(float4*)&Vs[bufi][sr+ 0][sk] = vr0; \
        *(float4*)&Vs[bufi][sr+16][sk] = vr1; \
        *(float4*)&Vs[bufi][sr+32][sk] = vr2; \
        *(float4*)&Vs[bufi][sr+48][sk] = vr3; }

    float m0 = -1e30f, m1 = -1e30f, l0 = 0.f, l1 = 0.f;
    float acc0[32] = {}, acc1[32] = {};

    const int NT = S_ / 64;                   // 48 tiles

    // prologue: tile 0 into buf0, tile 1 into regs
    LOAD_TILE(0);
    WRITE_TILE(0);
    LOAD_TILE(64);
    __syncthreads();

    for (int t = 0; t < NT; ++t) {
        const int cur = t & 1;
        const int nxt = cur ^ 1;
        if (t + 1 < NT) {
            WRITE_TILE(nxt);                  // tile t+1 regs -> other buffer
            if (t + 2 < NT) LOAD_TILE((t + 2) * 64);  // refill regs; hides under compute
        }

        const float (*Kc)[36] = Ks[cur];
        const float (*Vc)[36] = Vs[cur];

        __builtin_amdgcn_s_setprio(1);
        // ---- scores for 16 cols x 2 rows (Ks read shared across both rows)
        float sc0[16], sc1[16];
        #pragma unroll
        for (int i = 0; i < 16; ++i) {
            const int c = sub + 4*i;           // 4 distinct addrs/instr, 16-lane broadcast
            float d0 = 0.f, d1 = 0.f;
            #pragma unroll
            for (int k4 = 0; k4 < 32; k4 += 4) {
                float4 kk = *(const float4*)&Kc[c][k4];
                d0 += qreg0[k4+0]*kk.x + qreg0[k4+1]*kk.y + qreg0[k4+2]*kk.z + qreg0[k4+3]*kk.w;
                d1 += qreg1[k4+0]*kk.x + qreg1[k4+1]*kk.y + qreg1[k4+2]*kk.z + qreg1[k4+3]*kk.w;
            }
            sc0[i] = d0; sc1[i] = d1;
        }

        // ---- online softmax bookkeeping, both rows (tree reductions)
        {
            float tm0 = tree_max16(sc0);
            float tm1 = tree_max16(sc1);
            tm0 = fmaxf(tm0, __shfl_xor(tm0, 1));
            tm0 = fmaxf(tm0, __shfl_xor(tm0, 2));
            tm1 = fmaxf(tm1, __shfl_xor(tm1, 1));
            tm1 = fmaxf(tm1, __shfl_xor(tm1, 2));
            const float mnew0 = fmaxf(m0, tm0);
            const float mnew1 = fmaxf(m1, tm1);
            const float f0 = __expf(m0 - mnew0);
            const float f1 = __expf(m1 - mnew1);
            m0 = mnew0; m1 = mnew1; l0 *= f0; l1 *= f1;
            #pragma unroll
            for (int dd = 0; dd < 32; ++dd) { acc0[dd] *= f0; acc1[dd] *= f1; }
            #pragma unroll
            for (int i = 0; i < 16; ++i) {
                sc0[i] = __expf(sc0[i] - mnew0);
                sc1[i] = __expf(sc1[i] - mnew1);
            }
            l0 += tree_sum16(sc0);
            l1 += tree_sum16(sc1);
        }

        // ---- PV, fused over both rows: each Vs float4 read feeds 8 FMAs
        #pragma unroll
        for (int i = 0; i < 16; ++i) {
            const int c = sub + 4*i;
            const float p0 = sc0[i];
            const float p1 = sc1[i];
            #pragma unroll
            for (int d4 = 0; d4 < 8; ++d4) {
                float4 vv = *(const float4*)&Vc[c][d4*4];
                acc0[d4*4+0] += p0*vv.x; acc0[d4*4+1] += p0*vv.y;
                acc0[d4*4+2] += p0*vv.z; acc0[d4*4+3] += p0*vv.w;
                acc1[d4*4+0] += p1*vv.x; acc1[d4*4+1] += p1*vv.y;
                acc1[d4*4+2] += p1*vv.z; acc1[d4*4+3] += p1*vv.w;
            }
        }
        __builtin_amdgcn_s_setprio(0);

        __syncthreads();                       // single barrier per tile
    }

#undef LOAD_TILE
#undef WRITE_TILE

    // ---- reduce across the 4-lane row group, normalize, write
    l0 += __shfl_xor(l0, 1); l0 += __shfl_xor(l0, 2);
    l1 += __shfl_xor(l1, 1); l1 += __shfl_xor(l1, 2);
    const float inv0 = 1.f / l0, inv1 = 1.f / l1;
    #pragma unroll
    for (int dd = 0; dd < 32; ++dd) {
        float a = acc0[dd]; a += __shfl_xor(a, 1); a += __shfl_xor(a, 2); acc0[dd] = a * inv0;
        float c2 = acc1[dd]; c2 += __shfl_xor(c2, 1); c2 += __shfl_xor(c2, 2); acc1[dd] = c2 * inv1;
    }
    // static-index writes: 4-way branch on sub (keeps register arrays out of scratch)
    #define WRITE_SLICE(ro, a_, off) { \
        float4 o1 = make_float4(a_[(off)+0],a_[(off)+1],a_[(off)+2],a_[(off)+3]); \
        float4 o2 = make_float4(a_[(off)+4],a_[(off)+5],a_[(off)+6],a_[(off)+7]); \
        *(float4*)&ctx[(rowbase + (ro))*C_ + coloff + (off)]     = o1; \
        *(float4*)&ctx[(rowbase + (ro))*C_ + coloff + (off) + 4] = o2; }
    if      (sub == 0) { WRITE_SLICE(r0, acc0, 0)  WRITE_SLICE(r1, acc1, 0)  }
    else if (sub == 1) { WRITE_SLICE(r0, acc0, 8)  WRITE_SLICE(r1, acc1, 8)  }
    else if (sub == 2) { WRITE_SLICE(r0, acc0, 16) WRITE_SLICE(r1, acc1, 16) }
    else               { WRITE_SLICE(r0, acc0, 24) WRITE_SLICE(r1, acc1, 24) }
    #undef WRITE_SLICE
}

// ---------------- launch ---------------------------------------------------------
extern "C" void kernel_launch(void* const* d_in, const int* in_sizes, int n_in,
                              void* d_out, int out_size, void* d_ws, size_t ws_size,
                              hipStream_t stream)
{
    const float* x  = (const float*)d_in[0];
    const float* Wq = (const float*)d_in[1];
    const float* Wk = (const float*)d_in[2];
    const float* Wv = (const float*)d_in[3];
    const float* qb = (const float*)d_in[4];
    const float* vb = (const float*)d_in[5];
    const float* Wo = (const float*)d_in[6];
    const float* bo = (const float*)d_in[7];
    float* out = (float*)d_out;

    float* ws  = (float*)d_ws;
    float* q   = ws;
    float* k   = q + NELEM;
    float* v   = k + NELEM;
    float* ctx = v + NELEM;

    // q,k,v projections (+bias), 64x64 tiles: grid 96 x 4, z selects matrix
    qkv_kernel<<<dim3(96, 4, 3), 256, 0, stream>>>(x, Wq, Wk, Wv, qb, vb, q, k, v);
    // RoPE in place on q (scale folded later) and k
    rope_kernel<<<6144, 256, 0, stream>>>(q, k);
    // flash attention: 768 blocks of 128 threads (64 q-rows each), pipelined staging
    attn_kernel<<<dim3(S_/64, NH, B_), 128, 0, stream>>>(q, k, v, ctx);
    // output projection
    out_gemm_kernel<<<dim3(96, 4, 1), 256, 0, stream>>>(ctx, Wo, bo, out);
}